// Round 2
// baseline (552.277 us; speedup 1.0000x reference)
//
#include <hip/hip_runtime.h>
#include <hip/hip_bf16.h>

#define S_DIM 256
#define I_DIM 512
#define C_DIM 256
#define NROWS (S_DIM * I_DIM)  // 131072

using bf16x8 = __attribute__((ext_vector_type(8))) short;
using f32x4  = __attribute__((ext_vector_type(4))) float;

__device__ __forceinline__ unsigned short f2bf(float f) {
  unsigned int u = __builtin_bit_cast(unsigned int, f);
  u += 0x7fffu + ((u >> 16) & 1u);   // round-to-nearest-even
  return (unsigned short)(u >> 16);
}

// ---------------------------------------------------------------------------
// K0: cast+transpose weights to bf16; zero xbar accumulator.
// WkvT[n][c] (n<32: Wk col n, n>=32: Wv col n-32); WgT[n][c]=Wg[c][n]; WoT[n][c]=Wo[c][n]
// ---------------------------------------------------------------------------
__global__ __launch_bounds__(256) void prep_weights(
    const float* __restrict__ Wk, const float* __restrict__ Wv,
    const float* __restrict__ Wg, const float* __restrict__ Wo,
    unsigned short* __restrict__ WkvT, unsigned short* __restrict__ WgT,
    unsigned short* __restrict__ WoT, float* __restrict__ xbar) {
  int t = blockIdx.x * 256 + threadIdx.x;       // 65536 threads
  int n = t >> 8, c = t & 255;
  if (t < 64 * 256) {
    float v = (n < 32) ? Wk[c * 32 + n] : Wv[c * 32 + (n - 32)];
    WkvT[t] = f2bf(v);
  }
  WgT[t] = f2bf(Wg[c * 256 + n]);
  WoT[t] = f2bf(Wo[c * 256 + n]);
  xbar[t] = 0.f;
  xbar[t + 65536] = 0.f;
}

// ---------------------------------------------------------------------------
// K1: LayerNorm per (s,i) row -> xn (bf16), plus sum over s into xbar (atomics).
// Block = 4 waves, each wave one row; all 4 rows share the same i.
// ---------------------------------------------------------------------------
__global__ __launch_bounds__(256) void ln_kernel(
    const float* __restrict__ x, const float* __restrict__ gamma,
    const float* __restrict__ beta, unsigned short* __restrict__ xn,
    float* __restrict__ xbar) {
  int b = blockIdx.x;                  // 32768
  int i = b & (I_DIM - 1);
  int sg = b >> 9;                     // 0..63
  int w = threadIdx.x >> 6;
  int lane = threadIdx.x & 63;
  int s = sg * 4 + w;
  int row = s * I_DIM + i;

  const float4 xv = *(const float4*)(x + (size_t)row * 256 + lane * 4);
  float sum = xv.x + xv.y + xv.z + xv.w;
  float sq  = xv.x*xv.x + xv.y*xv.y + xv.z*xv.z + xv.w*xv.w;
#pragma unroll
  for (int off = 32; off >= 1; off >>= 1) {
    sum += __shfl_xor(sum, off);
    sq  += __shfl_xor(sq, off);
  }
  float mu = sum * (1.f / 256.f);
  float rs = rsqrtf(sq * (1.f / 256.f) - mu * mu + 1e-5f);
  float4 gv = *(const float4*)(gamma + lane * 4);
  float4 bv = *(const float4*)(beta + lane * 4);
  float y0 = (xv.x - mu) * rs * gv.x + bv.x;
  float y1 = (xv.y - mu) * rs * gv.y + bv.y;
  float y2 = (xv.z - mu) * rs * gv.z + bv.z;
  float y3 = (xv.w - mu) * rs * gv.w + bv.w;

  ushort4 o;
  o.x = f2bf(y0); o.y = f2bf(y1); o.z = f2bf(y2); o.w = f2bf(y3);
  *(ushort4*)(xn + (size_t)row * 256 + lane * 4) = o;

  __shared__ float acc[256];
  acc[threadIdx.x] = 0.f;
  __syncthreads();
  atomicAdd(&acc[lane * 4 + 0], y0);
  atomicAdd(&acc[lane * 4 + 1], y1);
  atomicAdd(&acc[lane * 4 + 2], y2);
  atomicAdd(&acc[lane * 4 + 3], y3);
  __syncthreads();
  atomicAdd(&xbar[i * 256 + threadIdx.x], acc[threadIdx.x]);
}

// ---------------------------------------------------------------------------
// K2: Q[i][col] = (xbar_sum[i]/S) @ Wq * (1/sqrt(D))   [512 x 256 tiny GEMM]
// ---------------------------------------------------------------------------
__global__ __launch_bounds__(256) void q_kernel(
    const float* __restrict__ xbar, const float* __restrict__ Wq,
    float* __restrict__ Q) {
  int i = blockIdx.x, col = threadIdx.x;
  __shared__ float xr[256];
  xr[col] = xbar[i * 256 + col] * (1.f / 256.f);
  __syncthreads();
  float acc = 0.f;
#pragma unroll 8
  for (int c = 0; c < 256; ++c) acc = fmaf(xr[c], Wq[c * 256 + col], acc);
  Q[i * 256 + col] = acc * 0.17677669529663687f;   // 1/sqrt(32)
}

// ---------------------------------------------------------------------------
// K3: KV[row][0:64] = xn[row] @ [Wk|Wv]  via bf16 MFMA. M-tile=64, block=4 waves.
// ---------------------------------------------------------------------------
__global__ __launch_bounds__(256) void kv_kernel(
    const unsigned short* __restrict__ xn, const unsigned short* __restrict__ WkvT,
    float* __restrict__ KV) {
  __shared__ __attribute__((aligned(16))) unsigned short xs[64 * 264];
  __shared__ __attribute__((aligned(16))) unsigned short wt[64 * 264];
  int tid = threadIdx.x;
  int m0 = blockIdx.x * 64;

  const uint4* xg = (const uint4*)(xn + (size_t)m0 * 256);
#pragma unroll
  for (int j = 0; j < 8; ++j) {
    int idx = tid + j * 256;
    *(uint4*)(&xs[(idx >> 5) * 264 + (idx & 31) * 8]) = xg[idx];
  }
  // weight tile: 64 rows x 256 shorts = 2048 uint4  (was j<4 = HALF -> NaN bug)
  const uint4* wg_ = (const uint4*)WkvT;
#pragma unroll
  for (int j = 0; j < 8; ++j) {
    int idx = tid + j * 256;
    *(uint4*)(&wt[(idx >> 5) * 264 + (idx & 31) * 8]) = wg_[idx];
  }
  __syncthreads();

  int w = tid >> 6, lane = tid & 63;
  int m15 = lane & 15, q = lane >> 4;
  f32x4 acc[4] = {};
#pragma unroll
  for (int k = 0; k < 8; ++k) {
    bf16x8 a = *(const bf16x8*)(&xs[(w * 16 + m15) * 264 + k * 32 + q * 8]);
#pragma unroll
    for (int nt = 0; nt < 4; ++nt) {
      bf16x8 bb = *(const bf16x8*)(&wt[(nt * 16 + m15) * 264 + k * 32 + q * 8]);
      acc[nt] = __builtin_amdgcn_mfma_f32_16x16x32_bf16(a, bb, acc[nt], 0, 0, 0);
    }
  }
#pragma unroll
  for (int nt = 0; nt < 4; ++nt)
#pragma unroll
    for (int r = 0; r < 4; ++r)
      KV[(size_t)(m0 + w * 16 + q * 4 + r) * 64 + nt * 16 + m15] = acc[nt][r];
}

// ---------------------------------------------------------------------------
// K4: per-residue-i attention: scores(8 heads x 256 rows) -> softmax over rows
//     -> weighted[i][h*32+d]. One block per i.
// ---------------------------------------------------------------------------
__global__ __launch_bounds__(256) void attn_kernel(
    const float* __restrict__ KV, const float* __restrict__ Q,
    float* __restrict__ weighted) {
  __shared__ __attribute__((aligned(16))) float kv[256 * 68];  // K: d 0..31, V: 32..63
  __shared__ float sl[8 * 264];
  __shared__ float ql[256];
  int i = blockIdx.x, tid = threadIdx.x;

  ql[tid] = Q[i * 256 + tid];
  const float4* src = (const float4*)(KV + ((size_t)tid * I_DIM + i) * 64);
#pragma unroll
  for (int j = 0; j < 16; ++j) *(float4*)(&kv[tid * 68 + j * 4]) = src[j];
  __syncthreads();

  // scores: thread tid = row t
  float kr[32];
#pragma unroll
  for (int j = 0; j < 8; ++j)
    *(float4*)(&kr[j * 4]) = *(const float4*)(&kv[tid * 68 + j * 4]);
#pragma unroll
  for (int h = 0; h < 8; ++h) {
    float sc = 0.f;
#pragma unroll
    for (int d = 0; d < 32; ++d) sc = fmaf(kr[d], ql[h * 32 + d], sc);
    sl[h * 264 + tid] = sc;
  }
  __syncthreads();

  // softmax over t for 2 heads per wave
  int w = tid >> 6, lane = tid & 63;
#pragma unroll
  for (int hh = 0; hh < 2; ++hh) {
    int h = w * 2 + hh;
    float v0 = sl[h * 264 + lane], v1 = sl[h * 264 + lane + 64];
    float v2 = sl[h * 264 + lane + 128], v3 = sl[h * 264 + lane + 192];
    float m = fmaxf(fmaxf(v0, v1), fmaxf(v2, v3));
#pragma unroll
    for (int off = 32; off >= 1; off >>= 1) m = fmaxf(m, __shfl_xor(m, off));
    float e0 = __expf(v0 - m), e1 = __expf(v1 - m);
    float e2 = __expf(v2 - m), e3 = __expf(v3 - m);
    float ssum = e0 + e1 + e2 + e3;
#pragma unroll
    for (int off = 32; off >= 1; off >>= 1) ssum += __shfl_xor(ssum, off);
    float inv = 1.f / ssum;
    sl[h * 264 + lane] = e0 * inv;
    sl[h * 264 + lane + 64] = e1 * inv;
    sl[h * 264 + lane + 128] = e2 * inv;
    sl[h * 264 + lane + 192] = e3 * inv;
  }
  __syncthreads();

  // weighted[i][h*32+d] = sum_t attn[h][t] * V[t][d]
  int h = tid >> 5, d = tid & 31;
  float acc = 0.f;
  for (int t = 0; t < 256; ++t)
    acc = fmaf(sl[h * 264 + t], kv[t * 68 + 32 + d], acc);
  weighted[i * 256 + tid] = acc;
}

// ---------------------------------------------------------------------------
// K5: fused G=sigmoid(x@Wg+bg); val=G*weighted[i]; out=val@Wo+bo.
// M-tile=64 rows, 4 waves; weights streamed through LDS in 64-col chunks.
// ---------------------------------------------------------------------------
__global__ __launch_bounds__(256) void fused_out_kernel(
    const unsigned short* __restrict__ xn, const unsigned short* __restrict__ WgT,
    const unsigned short* __restrict__ WoT, const float* __restrict__ weighted,
    const float* __restrict__ bg, const float* __restrict__ bo,
    float* __restrict__ out) {
  __shared__ __attribute__((aligned(16))) unsigned short xs[64 * 264];
  __shared__ __attribute__((aligned(16))) unsigned short wsl[64 * 264];
  __shared__ __attribute__((aligned(16))) unsigned short val[64 * 264];
  int tid = threadIdx.x;
  int m0 = blockIdx.x * 64;

  const uint4* xg = (const uint4*)(xn + (size_t)m0 * 256);
#pragma unroll
  for (int j = 0; j < 8; ++j) {
    int idx = tid + j * 256;
    *(uint4*)(&xs[(idx >> 5) * 264 + (idx & 31) * 8]) = xg[idx];
  }

  int w = tid >> 6, lane = tid & 63;
  int m15 = lane & 15, q = lane >> 4;
  int mrow = w * 16 + m15;
  int orow = w * 16 + q * 4;

#pragma unroll 1
  for (int phase = 0; phase < 2; ++phase) {
    const uint4* Wsrc = (const uint4*)(phase ? WoT : WgT);
    const unsigned short* asrc = phase ? val : xs;
#pragma unroll 1
    for (int ch = 0; ch < 4; ++ch) {
      __syncthreads();                 // wsl (and val in phase transition) safe
      // weight chunk: 64 rows x 256 shorts = 2048 uint4 (was j<4 + ch*1024 bug)
#pragma unroll
      for (int j = 0; j < 8; ++j) {
        int idx = tid + j * 256;
        *(uint4*)(&wsl[(idx >> 5) * 264 + (idx & 31) * 8]) = Wsrc[ch * 2048 + idx];
      }
      __syncthreads();

      f32x4 acc[4] = {};
#pragma unroll
      for (int k = 0; k < 8; ++k) {
        bf16x8 a = *(const bf16x8*)(&asrc[mrow * 264 + k * 32 + q * 8]);
#pragma unroll
        for (int nt = 0; nt < 4; ++nt) {
          bf16x8 bb = *(const bf16x8*)(&wsl[(nt * 16 + m15) * 264 + k * 32 + q * 8]);
          acc[nt] = __builtin_amdgcn_mfma_f32_16x16x32_bf16(a, bb, acc[nt], 0, 0, 0);
        }
      }

      if (phase == 0) {
#pragma unroll
        for (int nt = 0; nt < 4; ++nt) {
          int col = ch * 64 + nt * 16 + m15;
          float bgi = bg[col];
#pragma unroll
          for (int r = 0; r < 4; ++r) {
            int rowg = m0 + orow + r;
            float pre = acc[nt][r] + bgi;
            float g = 1.f / (1.f + __expf(-pre));
            float vv = g * weighted[(rowg & (I_DIM - 1)) * 256 + col];
            val[(orow + r) * 264 + col] = f2bf(vv);
          }
        }
      } else {
#pragma unroll
        for (int nt = 0; nt < 4; ++nt) {
          int col = ch * 64 + nt * 16 + m15;
          float boi = bo[col];
#pragma unroll
          for (int r = 0; r < 4; ++r) {
            int rowg = m0 + orow + r;
            out[(size_t)rowg * 256 + col] = acc[nt][r] + boi;
          }
        }
      }
    }
  }
}

// ---------------------------------------------------------------------------
extern "C" void kernel_launch(void* const* d_in, const int* in_sizes, int n_in,
                              void* d_out, int out_size, void* d_ws, size_t ws_size,
                              hipStream_t stream) {
  const float* msa = (const float*)d_in[0];
  const float* gam = (const float*)d_in[1];
  const float* bet = (const float*)d_in[2];
  const float* Wq  = (const float*)d_in[3];
  const float* Wk  = (const float*)d_in[4];
  const float* Wv  = (const float*)d_in[5];
  const float* Wg  = (const float*)d_in[6];
  const float* bg  = (const float*)d_in[7];
  const float* Wo  = (const float*)d_in[8];
  const float* bo  = (const float*)d_in[9];
  float* out = (float*)d_out;

  char* ws = (char*)d_ws;
  unsigned short* xn   = (unsigned short*)ws;               // 67,108,864 B
  float* xbar          = (float*)(ws + 67108864);           //    524,288 B (sums)
  float* Q             = (float*)(ws + 67633152);           //    524,288 B
  float* KV            = (float*)(ws + 68157440);           // 33,554,432 B
  float* weighted      = (float*)(ws + 101711872);          //    524,288 B
  unsigned short* WkvT = (unsigned short*)(ws + 102236160); //     32,768 B
  unsigned short* WgT  = (unsigned short*)(ws + 102268928); //    131,072 B
  unsigned short* WoT  = (unsigned short*)(ws + 102400000); //    131,072 B

  prep_weights<<<256, 256, 0, stream>>>(Wk, Wv, Wg, Wo, WkvT, WgT, WoT, xbar);
  ln_kernel<<<32768, 256, 0, stream>>>(msa, gam, bet, xn, xbar);
  q_kernel<<<512, 256, 0, stream>>>(xbar, Wq, Q);
  kv_kernel<<<2048, 256, 0, stream>>>(xn, WkvT, KV);
  attn_kernel<<<512, 256, 0, stream>>>(KV, Q, weighted);
  fused_out_kernel<<<2048, 256, 0, stream>>>(xn, WgT, WoT, weighted, bg, bo, out);
}

// Round 3
// 383.214 us; speedup vs baseline: 1.4412x; 1.4412x over previous
//
#include <hip/hip_runtime.h>
#include <hip/hip_bf16.h>

#define S_DIM 256
#define I_DIM 512
#define NROWS (S_DIM * I_DIM)  // 131072

using bf16x8 = __attribute__((ext_vector_type(8))) short;
using f32x4  = __attribute__((ext_vector_type(4))) float;
typedef unsigned short ushort_t;

__device__ __forceinline__ unsigned short f2bf(float f) {
  unsigned int u = __builtin_bit_cast(unsigned int, f);
  u += 0x7fffu + ((u >> 16) & 1u);   // RNE
  return (unsigned short)(u >> 16);
}
__device__ __forceinline__ float bf2f(unsigned short u) {
  unsigned int x = ((unsigned int)u) << 16;
  return __builtin_bit_cast(float, x);
}
// async global->LDS, 16 B per lane; LDS dst = wave-uniform base + lane*16
__device__ __forceinline__ void gl_lds16(const void* g, void* l) {
  __builtin_amdgcn_global_load_lds(
      (const __attribute__((address_space(1))) void*)g,
      (__attribute__((address_space(3))) void*)l, 16, 0, 0);
}

// ---------------------------------------------------------------------------
// K0: cast+transpose weights to bf16.
// ---------------------------------------------------------------------------
__global__ __launch_bounds__(256) void prep_weights(
    const float* __restrict__ Wk, const float* __restrict__ Wv,
    const float* __restrict__ Wg, const float* __restrict__ Wo,
    ushort_t* __restrict__ WkvT, ushort_t* __restrict__ WgT,
    ushort_t* __restrict__ WoT) {
  int t = blockIdx.x * 256 + threadIdx.x;       // 65536 threads
  int n = t >> 8, c = t & 255;
  if (t < 64 * 256) {
    float v = (n < 32) ? Wk[c * 32 + n] : Wv[c * 32 + (n - 32)];
    WkvT[t] = f2bf(v);
  }
  WgT[t] = f2bf(Wg[c * 256 + n]);
  WoT[t] = f2bf(Wo[c * 256 + n]);
}

// ---------------------------------------------------------------------------
// K1: LayerNorm -> xn (bf16) + per-block partial column sums (NO atomics).
// Block b: i = b&511, sq = b>>9; wave w handles s = sq*64 + w*16 + it.
// ---------------------------------------------------------------------------
__global__ __launch_bounds__(256) void ln_kernel(
    const float* __restrict__ x, const float* __restrict__ gamma,
    const float* __restrict__ beta, ushort_t* __restrict__ xn,
    float* __restrict__ xpart) {
  __shared__ float sacc[4][256];
  int b = blockIdx.x;                  // 2048
  int i = b & (I_DIM - 1);
  int sq = b >> 9;                     // 0..3
  int w = threadIdx.x >> 6;
  int lane = threadIdx.x & 63;

  float4 gv = *(const float4*)(gamma + lane * 4);
  float4 bv = *(const float4*)(beta + lane * 4);
  float p0 = 0.f, p1 = 0.f, p2 = 0.f, p3 = 0.f;

#pragma unroll 4
  for (int it = 0; it < 16; ++it) {
    int s = sq * 64 + w * 16 + it;
    size_t row = (size_t)s * I_DIM + i;
    float4 xv = *(const float4*)(x + row * 256 + lane * 4);
    float sum = xv.x + xv.y + xv.z + xv.w;
    float sq2 = xv.x*xv.x + xv.y*xv.y + xv.z*xv.z + xv.w*xv.w;
#pragma unroll
    for (int off = 32; off >= 1; off >>= 1) {
      sum += __shfl_xor(sum, off);
      sq2 += __shfl_xor(sq2, off);
    }
    float mu = sum * (1.f / 256.f);
    float rs = rsqrtf(sq2 * (1.f / 256.f) - mu * mu + 1e-5f);
    float y0 = (xv.x - mu) * rs * gv.x + bv.x;
    float y1 = (xv.y - mu) * rs * gv.y + bv.y;
    float y2 = (xv.z - mu) * rs * gv.z + bv.z;
    float y3 = (xv.w - mu) * rs * gv.w + bv.w;
    ushort4 o;
    o.x = f2bf(y0); o.y = f2bf(y1); o.z = f2bf(y2); o.w = f2bf(y3);
    *(ushort4*)(xn + row * 256 + lane * 4) = o;
    p0 += y0; p1 += y1; p2 += y2; p3 += y3;
  }
  sacc[w][lane * 4 + 0] = p0;
  sacc[w][lane * 4 + 1] = p1;
  sacc[w][lane * 4 + 2] = p2;
  sacc[w][lane * 4 + 3] = p3;
  __syncthreads();
  int tid = threadIdx.x;
  xpart[((size_t)sq * I_DIM + i) * 256 + tid] =
      sacc[0][tid] + sacc[1][tid] + sacc[2][tid] + sacc[3][tid];
}

// ---------------------------------------------------------------------------
// K2: Q[i][col] = mean_s(xn) @ Wq * (1/sqrt(D)); reduces the 4 partials.
// ---------------------------------------------------------------------------
__global__ __launch_bounds__(256) void q_kernel(
    const float* __restrict__ xpart, const float* __restrict__ Wq,
    float* __restrict__ Q) {
  int i = blockIdx.x, col = threadIdx.x;
  __shared__ float xr[256];
  float s = xpart[((size_t)0 * I_DIM + i) * 256 + col]
          + xpart[((size_t)1 * I_DIM + i) * 256 + col]
          + xpart[((size_t)2 * I_DIM + i) * 256 + col]
          + xpart[((size_t)3 * I_DIM + i) * 256 + col];
  xr[col] = s * (1.f / 256.f);
  __syncthreads();
  float acc = 0.f;
#pragma unroll 8
  for (int c = 0; c < 256; ++c) acc = fmaf(xr[c], Wq[c * 256 + col], acc);
  Q[i * 256 + col] = acc * 0.17677669529663687f;   // 1/sqrt(32)
}

// ---------------------------------------------------------------------------
// K3: KV[row][0:64] = xn[row] @ [Wk|Wv], bf16 output. 64-row tile, 4 waves.
// ---------------------------------------------------------------------------
__global__ __launch_bounds__(256) void kv_kernel(
    const ushort_t* __restrict__ xn, const ushort_t* __restrict__ WkvT,
    ushort_t* __restrict__ KVb) {
  __shared__ __attribute__((aligned(16))) ushort_t xs[64 * 264];
  __shared__ __attribute__((aligned(16))) ushort_t wt[64 * 264];
  int tid = threadIdx.x;
  int m0 = blockIdx.x * 64;

  const uint4* xg = (const uint4*)(xn + (size_t)m0 * 256);
#pragma unroll
  for (int j = 0; j < 8; ++j) {
    int idx = tid + j * 256;
    *(uint4*)(&xs[(idx >> 5) * 264 + (idx & 31) * 8]) = xg[idx];
  }
  const uint4* wg_ = (const uint4*)WkvT;
#pragma unroll
  for (int j = 0; j < 8; ++j) {
    int idx = tid + j * 256;
    *(uint4*)(&wt[(idx >> 5) * 264 + (idx & 31) * 8]) = wg_[idx];
  }
  __syncthreads();

  int w = tid >> 6, lane = tid & 63;
  int m15 = lane & 15, q = lane >> 4;
  f32x4 acc[4] = {};
#pragma unroll
  for (int k = 0; k < 8; ++k) {
    bf16x8 a = *(const bf16x8*)(&xs[(w * 16 + m15) * 264 + k * 32 + q * 8]);
#pragma unroll
    for (int nt = 0; nt < 4; ++nt) {
      bf16x8 bb = *(const bf16x8*)(&wt[(nt * 16 + m15) * 264 + k * 32 + q * 8]);
      acc[nt] = __builtin_amdgcn_mfma_f32_16x16x32_bf16(a, bb, acc[nt], 0, 0, 0);
    }
  }
#pragma unroll
  for (int nt = 0; nt < 4; ++nt)
#pragma unroll
    for (int r = 0; r < 4; ++r)
      KVb[(size_t)(m0 + w * 16 + q * 4 + r) * 64 + nt * 16 + m15] = f2bf(acc[nt][r]);
}

// ---------------------------------------------------------------------------
// K4: attention per residue i. K stays in registers; only V staged to LDS.
// ---------------------------------------------------------------------------
__global__ __launch_bounds__(256) void attn_kernel(
    const ushort_t* __restrict__ KVb, const float* __restrict__ Q,
    float* __restrict__ weighted) {
  __shared__ ushort_t Vs[256 * 36];    // stride 36 shorts: b64-aligned, 2-way banks
  __shared__ float sl[8 * 264];
  __shared__ float ql[256];
  int i = blockIdx.x, tid = threadIdx.x;

  ql[tid] = Q[i * 256 + tid];
  const uint4* src = (const uint4*)(KVb + ((size_t)tid * I_DIM + i) * 64);
  uint4 kr0 = src[0], kr1 = src[1], kr2 = src[2], kr3 = src[3];
#pragma unroll
  for (int j = 0; j < 4; ++j) {
    uint4 v = src[4 + j];
    *(ushort4*)(&Vs[tid * 36 + j * 8 + 0]) = *(ushort4*)&v.x;
    *(ushort4*)(&Vs[tid * 36 + j * 8 + 4]) = *(ushort4*)&v.z;
  }
  // unpack K to fp32
  ushort_t ks[32];
  *(uint4*)&ks[0] = kr0; *(uint4*)&ks[8] = kr1;
  *(uint4*)&ks[16] = kr2; *(uint4*)&ks[24] = kr3;
  float kf[32];
#pragma unroll
  for (int d = 0; d < 32; ++d) kf[d] = bf2f(ks[d]);
  __syncthreads();

#pragma unroll
  for (int h = 0; h < 8; ++h) {
    float sc = 0.f;
#pragma unroll
    for (int d = 0; d < 32; ++d) sc = fmaf(kf[d], ql[h * 32 + d], sc);
    sl[h * 264 + tid] = sc;
  }
  __syncthreads();

  int w = tid >> 6, lane = tid & 63;
#pragma unroll
  for (int hh = 0; hh < 2; ++hh) {
    int h = w * 2 + hh;
    float v0 = sl[h * 264 + lane], v1 = sl[h * 264 + lane + 64];
    float v2 = sl[h * 264 + lane + 128], v3 = sl[h * 264 + lane + 192];
    float m = fmaxf(fmaxf(v0, v1), fmaxf(v2, v3));
#pragma unroll
    for (int off = 32; off >= 1; off >>= 1) m = fmaxf(m, __shfl_xor(m, off));
    float e0 = __expf(v0 - m), e1 = __expf(v1 - m);
    float e2 = __expf(v2 - m), e3 = __expf(v3 - m);
    float ssum = e0 + e1 + e2 + e3;
#pragma unroll
    for (int off = 32; off >= 1; off >>= 1) ssum += __shfl_xor(ssum, off);
    float inv = 1.f / ssum;
    sl[h * 264 + lane] = e0 * inv;
    sl[h * 264 + lane + 64] = e1 * inv;
    sl[h * 264 + lane + 128] = e2 * inv;
    sl[h * 264 + lane + 192] = e3 * inv;
  }
  __syncthreads();

  int h = tid >> 5, d = tid & 31;
  float acc = 0.f;
#pragma unroll 4
  for (int t = 0; t < 256; ++t)
    acc = fmaf(sl[h * 264 + t], bf2f(Vs[t * 36 + d]), acc);
  weighted[i * 256 + tid] = acc;
}

// ---------------------------------------------------------------------------
// K5: fused G=sigmoid(xn@Wg+bg); val=G*weighted; out=val@Wo+bo.
// 128-row tile, 512 threads (8 waves = 2 rowgrp x 4 colgrp, 64x64 per wave).
// global_load_lds staging, XOR-swizzled LDS (16-B units), val kept in LDS.
// LDS: xA 16K + Bs 32K + valS 64K = 112 KB.
// ---------------------------------------------------------------------------
__global__ __launch_bounds__(512) void fused_out_kernel(
    const ushort_t* __restrict__ xn, const ushort_t* __restrict__ WgT,
    const ushort_t* __restrict__ WoT, const float* __restrict__ weighted,
    const float* __restrict__ bg, const float* __restrict__ bo,
    float* __restrict__ out) {
  __shared__ __attribute__((aligned(16))) ushort_t xA[128 * 64];
  __shared__ __attribute__((aligned(16))) ushort_t Bs[256 * 64];
  __shared__ __attribute__((aligned(16))) ushort_t valS[128 * 256];
  const int tid = threadIdx.x;
  const int m0 = blockIdx.x * 128;
  const int w = tid >> 6, lane = tid & 63;
  const int m15 = lane & 15, q = lane >> 4;
  const int r2 = w >> 2, c4 = w & 3;

  f32x4 acc[4][4];
  const f32x4 zero = {0.f, 0.f, 0.f, 0.f};
#pragma unroll
  for (int t = 0; t < 4; ++t)
#pragma unroll
    for (int nt = 0; nt < 4; ++nt) acc[t][nt] = zero;

  // -------- phase 0: pre-gate = xn @ Wg --------
#pragma unroll 1
  for (int kc = 0; kc < 4; ++kc) {
    __syncthreads();
    // stage xA chunk: 128 rows x 8 units (16 B) = 1024 units
#pragma unroll
    for (int it = 0; it < 2; ++it) {
      int L = it * 512 + tid;
      int r = L >> 3, u = (L & 7) ^ (r & 7);
      gl_lds16(xn + (size_t)(m0 + r) * 256 + kc * 64 + u * 8,
               &xA[(it * 512 + w * 64) * 8]);
    }
    // stage Bs chunk: 256 rows x 8 units = 2048 units
#pragma unroll
    for (int it = 0; it < 4; ++it) {
      int L = it * 512 + tid;
      int n = L >> 3, u = (L & 7) ^ (n & 7);
      gl_lds16(WgT + (size_t)n * 256 + kc * 64 + u * 8,
               &Bs[(it * 512 + w * 64) * 8]);
    }
    __syncthreads();
#pragma unroll
    for (int kk = 0; kk < 2; ++kk) {
      bf16x8 bf[4], af[4];
#pragma unroll
      for (int nt = 0; nt < 4; ++nt) {
        int n = c4 * 64 + nt * 16 + m15;
        bf[nt] = *(const bf16x8*)&Bs[n * 64 + (((kk * 4 + q) ^ (n & 7)) * 8)];
      }
#pragma unroll
      for (int t = 0; t < 4; ++t) {
        int m = r2 * 64 + t * 16 + m15;
        af[t] = *(const bf16x8*)&xA[m * 64 + (((kk * 4 + q) ^ (m & 7)) * 8)];
      }
#pragma unroll
      for (int t = 0; t < 4; ++t)
#pragma unroll
        for (int nt = 0; nt < 4; ++nt)
          acc[t][nt] = __builtin_amdgcn_mfma_f32_16x16x32_bf16(af[t], bf[nt], acc[t][nt], 0, 0, 0);
    }
  }

  // epilogue 0: sigmoid gate * weighted -> valS (bf16, swizzled)
#pragma unroll
  for (int nt = 0; nt < 4; ++nt) {
    int col = c4 * 64 + nt * 16 + m15;
    float bgi = bg[col];
#pragma unroll
    for (int t = 0; t < 4; ++t)
#pragma unroll
      for (int r = 0; r < 4; ++r) {
        int row = r2 * 64 + t * 16 + q * 4 + r;
        float pre = acc[t][nt][r] + bgi;
        float g = 1.f / (1.f + __expf(-pre));
        float vv = g * weighted[(size_t)((m0 + row) & (I_DIM - 1)) * 256 + col];
        valS[row * 256 + (((col >> 3) ^ (row & 7)) * 8) + (col & 7)] = f2bf(vv);
      }
  }
#pragma unroll
  for (int t = 0; t < 4; ++t)
#pragma unroll
    for (int nt = 0; nt < 4; ++nt) acc[t][nt] = zero;

  // -------- phase 1: out = val @ Wo + bo --------
#pragma unroll 1
  for (int kc = 0; kc < 4; ++kc) {
    __syncthreads();                 // val visible (kc=0) / Bs reads done
#pragma unroll
    for (int it = 0; it < 4; ++it) {
      int L = it * 512 + tid;
      int n = L >> 3, u = (L & 7) ^ (n & 7);
      gl_lds16(WoT + (size_t)n * 256 + kc * 64 + u * 8,
               &Bs[(it * 512 + w * 64) * 8]);
    }
    __syncthreads();
#pragma unroll
    for (int kk = 0; kk < 2; ++kk) {
      bf16x8 bf[4], af[4];
#pragma unroll
      for (int nt = 0; nt < 4; ++nt) {
        int n = c4 * 64 + nt * 16 + m15;
        bf[nt] = *(const bf16x8*)&Bs[n * 64 + (((kk * 4 + q) ^ (n & 7)) * 8)];
      }
#pragma unroll
      for (int t = 0; t < 4; ++t) {
        int m = r2 * 64 + t * 16 + m15;
        int u = kc * 8 + kk * 4 + q;
        af[t] = *(const bf16x8*)&valS[m * 256 + ((u ^ (m & 7)) * 8)];
      }
#pragma unroll
      for (int t = 0; t < 4; ++t)
#pragma unroll
        for (int nt = 0; nt < 4; ++nt)
          acc[t][nt] = __builtin_amdgcn_mfma_f32_16x16x32_bf16(af[t], bf[nt], acc[t][nt], 0, 0, 0);
    }
  }

  // epilogue 1: out = acc + bo
#pragma unroll
  for (int nt = 0; nt < 4; ++nt) {
    int col = c4 * 64 + nt * 16 + m15;
    float boi = bo[col];
#pragma unroll
    for (int t = 0; t < 4; ++t)
#pragma unroll
      for (int r = 0; r < 4; ++r) {
        int row = r2 * 64 + t * 16 + q * 4 + r;
        out[(size_t)(m0 + row) * 256 + col] = acc[t][nt][r] + boi;
      }
  }
}

// ---------------------------------------------------------------------------
extern "C" void kernel_launch(void* const* d_in, const int* in_sizes, int n_in,
                              void* d_out, int out_size, void* d_ws, size_t ws_size,
                              hipStream_t stream) {
  const float* msa = (const float*)d_in[0];
  const float* gam = (const float*)d_in[1];
  const float* bet = (const float*)d_in[2];
  const float* Wq  = (const float*)d_in[3];
  const float* Wk  = (const float*)d_in[4];
  const float* Wv  = (const float*)d_in[5];
  const float* Wg  = (const float*)d_in[6];
  const float* bg  = (const float*)d_in[7];
  const float* Wo  = (const float*)d_in[8];
  const float* bo  = (const float*)d_in[9];
  float* out = (float*)d_out;

  char* ws = (char*)d_ws;
  ushort_t* xn     = (ushort_t*)ws;                    // 67,108,864 B
  float* xpart     = (float*)(ws + 67108864);          //  2,097,152 B
  float* Q         = (float*)(ws + 69206016);          //    524,288 B
  ushort_t* KVb    = (ushort_t*)(ws + 69730304);       // 16,777,216 B
  float* weighted  = (float*)(ws + 86507520);          //    524,288 B
  ushort_t* WkvT   = (ushort_t*)(ws + 87031808);       //     32,768 B
  ushort_t* WgT    = (ushort_t*)(ws + 87064576);       //    131,072 B
  ushort_t* WoT    = (ushort_t*)(ws + 87195648);       //    131,072 B

  prep_weights<<<256, 256, 0, stream>>>(Wk, Wv, Wg, Wo, WkvT, WgT, WoT);
  ln_kernel<<<2048, 256, 0, stream>>>(msa, gam, bet, xn, xpart);
  q_kernel<<<512, 256, 0, stream>>>(xpart, Wq, Q);
  kv_kernel<<<2048, 256, 0, stream>>>(xn, WkvT, KVb);
  attn_kernel<<<512, 256, 0, stream>>>(KVb, Q, weighted);
  fused_out_kernel<<<1024, 512, 0, stream>>>(xn, WgT, WoT, weighted, bg, bo, out);
}